// Round 4
// baseline (252.931 us; speedup 1.0000x reference)
//
#include <hip/hip_runtime.h>

// set_transform: out[i,j,q,e] = sum_{h,k} relu((x_j W1)[q,h,:]·(y_j W2)[k,h,:]/8)/128 * (y_i W34)[k,h,e]
// W34[c, h*64+e] = sum_d W3[c,h*64+d] W4[h*64+d,e]  (fuses final @W4 into V-proj).
// All matmuls: bf16 hi/lo split MFMA (hh+hl+lh) -> absmax 9.8e-4 (passes, validated R2/R3).
//
// R4 changes (out_gemm: MfmaUtil 36%, 1.26e7 bank-conflict cycles = 37% of CU cycles):
//  - conflict-free subtiled LDS layout [R/16][BK/8][16][8]: frag ds_read_b128 is
//    contiguous-16B-per-lane (2-way banks = free). Permutation applied on the GLOBAL
//    source addr of global_load_lds; LDS dest stays linear (m104/rule-21).
//  - double-buffered 2-phase pipeline, BK=32: stage(next) issued BEFORE compute(cur),
//    single __syncthreads per K-tile (auto vmcnt+lgkmcnt drain). Was stage||compute serial.
//  - prep_w fused into prep_xy (one dispatch fewer).

#define MB (1u << 20)

typedef __attribute__((ext_vector_type(8))) short bf16x8;
typedef __attribute__((ext_vector_type(4))) float f32x4;

enum : size_t {
  OFF_XH  = 0,                       // later reused as A hi (attn output, 8MB spans XH+XL)
  OFF_XL  = OFF_XH  + 4 * MB,
  OFF_YH  = OFF_XL  + 4 * MB,        // later reused as A lo
  OFF_YL  = OFF_YH  + 4 * MB,
  OFF_W1H = OFF_YL  + 4 * MB,
  OFF_W1L = OFF_W1H + 512 * 1024,
  OFF_W2H = OFF_W1L + 512 * 1024,
  OFF_W2L = OFF_W2H + 512 * 1024,
  OFF_W3H = OFF_W2L + 512 * 1024,   // W34T hi
  OFF_W3L = OFF_W3H + 512 * 1024,   // W34T lo
  OFF_QH  = OFF_W3L + 512 * 1024,
  OFF_QL  = OFF_QH  + 4 * MB,
  OFF_KH  = OFF_QL  + 4 * MB,
  OFF_KL  = OFF_KH  + 4 * MB,
  OFF_VWH = OFF_KL  + 4 * MB,
  OFF_VWL = OFF_VWH + 4 * MB,
  WS_NEED = OFF_VWL + 4 * MB,       // 43 MB
  OFF_AH  = OFF_XH,                 // A hi/lo alias x/y split buffers (dead after proj_gemm)
  OFF_AL  = OFF_YH
};

__device__ __forceinline__ unsigned short f2bf(float f) {
  unsigned u = __builtin_bit_cast(unsigned, f);
  u += 0x7FFFu + ((u >> 16) & 1u);          // RNE
  return (unsigned short)(u >> 16);
}
__device__ __forceinline__ float bf2f(unsigned short h) {
  unsigned u = ((unsigned)h) << 16;
  return __builtin_bit_cast(float, u);
}
__device__ __forceinline__ void split2(float v, unsigned short& hi, unsigned short& lo) {
  hi = f2bf(v);
  lo = f2bf(v - bf2f(hi));
}

#define GLOAD_LDS16(g, l)                                                    \
  __builtin_amdgcn_global_load_lds(                                          \
      (const __attribute__((address_space(1))) void*)(g),                    \
      (__attribute__((address_space(3))) void*)(l), 16, 0, 0)

// ---------------------------------------------------------------------------
// prep: b<4096: split x,y f32 -> bf16 hi/lo (float4/thread).
//       b>=4096: W1/W2 transpose+split via padded LDS; W34 = per-head W3@W4.
// grid 4288 x 256
// ---------------------------------------------------------------------------
__global__ __launch_bounds__(256) void prep_all(
    const float* __restrict__ x, const float* __restrict__ y,
    const float* __restrict__ W1, const float* __restrict__ W2,
    const float* __restrict__ W3, const float* __restrict__ W4,
    unsigned short* xh, unsigned short* xl, unsigned short* yh, unsigned short* yl,
    unsigned short* w1h, unsigned short* w1l, unsigned short* w2h, unsigned short* w2l,
    unsigned short* w34h, unsigned short* w34l) {
  int b = blockIdx.x;
  if (b < 4096) {
    int idx = b * 256 + threadIdx.x;
    const float4* src; unsigned short *dh, *dl; int t;
    if (idx < 524288) { src = (const float4*)x; dh = xh; dl = xl; t = idx; }
    else              { src = (const float4*)y; dh = yh; dl = yl; t = idx - 524288; }
    float4 v = src[t];
    ushort4 hi, lo;
    split2(v.x, hi.x, lo.x); split2(v.y, hi.y, lo.y);
    split2(v.z, hi.z, lo.z); split2(v.w, hi.w, lo.w);
    *(ushort4*)&dh[t * 4] = hi;
    *(ushort4*)&dl[t * 4] = lo;
    return;
  }
  b -= 4096;
  if (b < 128) {
    __shared__ float lt[64][65];
    const float* W = (b < 64) ? W1 : W2;
    unsigned short* dh = (b < 64) ? w1h : w2h;
    unsigned short* dl = (b < 64) ? w1l : w2l;
    int t = b & 63;
    int cb = (t >> 3) * 64, nb = (t & 7) * 64;
#pragma unroll
    for (int it = 0; it < 16; ++it) {
      int idx = it * 256 + threadIdx.x;
      int cl = idx >> 6, nl = idx & 63;
      lt[cl][nl] = W[(cb + cl) * 512 + nb + nl];   // coalesced in n
    }
    __syncthreads();
#pragma unroll
    for (int it = 0; it < 16; ++it) {
      int idx = it * 256 + threadIdx.x;
      int nl = idx >> 6, cl = idx & 63;
      unsigned short hi, lo; split2(lt[cl][nl], hi, lo);
      dh[(nb + nl) * 512 + cb + cl] = hi;          // coalesced in c
      dl[(nb + nl) * 512 + cb + cl] = lo;
    }
  } else {
    __shared__ float l3[64][65];   // [c_local][d]
    __shared__ float l4[64][65];   // [d][e]
    int t = b - 128;
    int h = t >> 3, cb = (t & 7) * 64;
#pragma unroll
    for (int it = 0; it < 16; ++it) {
      int idx = it * 256 + threadIdx.x;
      int r = idx >> 6, cidx = idx & 63;
      l3[r][cidx] = W3[(cb + r) * 512 + h * 64 + cidx];    // coalesced in d
      l4[r][cidx] = W4[(h * 64 + r) * 64 + cidx];          // coalesced in e
    }
    __syncthreads();
#pragma unroll
    for (int pass = 0; pass < 16; ++pass) {
      int cl = threadIdx.x & 63;
      int el = pass * 4 + (threadIdx.x >> 6);
      float acc = 0.f;
#pragma unroll
      for (int d = 0; d < 64; ++d)
        acc += l3[cl][d] * l4[d][el];
      unsigned short hi, lo; split2(acc, hi, lo);
      w34h[(h * 64 + el) * 512 + cb + cl] = hi;
      w34l[(h * 64 + el) * 512 + cb + cl] = lo;
    }
  }
}

// ---------------------------------------------------------------------------
// GEMM core: BM x 128 tile, 4 waves (2x2), BK=32, double-buffered 2-phase.
// LDS layout per operand section: [R/16][BK/8=4][16 rows][8 k] bf16 subtiles.
//   - staging: LDS dest linear (gload_lds rule), global src permuted to match.
//   - frag read: lane reads 16B at ((fglob*4 + (lane>>4))*16 + (lane&15))*16
//     -> contiguous-16B-per-lane, 2-way banks = conflict-free.
// Pipeline: stage(buf0,0); sync; loop{ stage(next); compute(cur); sync; } compute(last).
// ---------------------------------------------------------------------------
template <int BM, int MF, int NF, int KTILES, typename EPI>
__device__ __forceinline__ void gemm_core(
    const unsigned short* __restrict__ Ahi, const unsigned short* __restrict__ Alo,
    const unsigned short* __restrict__ Bhi, const unsigned short* __restrict__ Blo,
    int row_stride_bytes, EPI&& epi) {
  constexpr int BN = 2 * NF * 16;          // 128 (WN=2)
  constexpr int ABYTES = BM * 64;          // BM rows x 32 k x 2B
  constexpr int BBYTES = BN * 64;
  constexpr int BUF = 2 * (ABYTES + BBYTES);
  constexpr int ITERS = BUF / 4096;        // 16B x 256 threads per iter
  static_assert(BUF % 4096 == 0 && ABYTES % 4096 == 0 && BBYTES % 4096 == 0, "");
  __shared__ alignas(16) char smem[2 * BUF];

  const int tid  = threadIdx.x;
  const int lane = tid & 63;
  const int wid  = tid >> 6;
  const int wm   = wid >> 1, wn = wid & 1;
  const int lr   = lane & 15;
  const int lg   = lane >> 4;              // k-slot 0..3

  f32x4 acc[MF][NF];
#pragma unroll
  for (int i = 0; i < MF; ++i)
#pragma unroll
    for (int j = 0; j < NF; ++j) acc[i][j] = (f32x4){0.f, 0.f, 0.f, 0.f};

  auto stage = [&](int cur, int kc) {
#pragma unroll
    for (int i = 0; i < ITERS; ++i) {
      int o = i * 4096 + wid * 1024 + lane * 16;
      const char* g; int lo_;
      if (o < ABYTES)                    { g = (const char*)Ahi; lo_ = o; }
      else if (o < 2 * ABYTES)           { g = (const char*)Alo; lo_ = o - ABYTES; }
      else if (o < 2 * ABYTES + BBYTES)  { g = (const char*)Bhi; lo_ = o - 2 * ABYTES; }
      else                               { g = (const char*)Blo; lo_ = o - 2 * ABYTES - BBYTES; }
      int idx16 = lo_ >> 4;
      int r  = idx16 & 15;
      int gg = (idx16 >> 4) & 3;
      int f  = idx16 >> 6;
      int row = f * 16 + r;
      GLOAD_LDS16(g + (size_t)row * row_stride_bytes + kc * 64 + gg * 16,
                  smem + cur * BUF + i * 4096 + wid * 1024);
    }
  };

  auto compute = [&](int cur) {
    const char* base = smem + cur * BUF;
    const char* secAh = base;
    const char* secAl = base + ABYTES;
    const char* secBh = base + 2 * ABYTES;
    const char* secBl = base + 2 * ABYTES + BBYTES;
    bf16x8 ah[MF], al[MF], bh[NF], bl[NF];
#pragma unroll
    for (int f = 0; f < MF; ++f) {
      int off = ((wm * MF + f) * 4 + lg) * 256 + lr * 16;
      ah[f] = *(const bf16x8*)(secAh + off);
      al[f] = *(const bf16x8*)(secAl + off);
    }
#pragma unroll
    for (int f = 0; f < NF; ++f) {
      int off = ((wn * NF + f) * 4 + lg) * 256 + lr * 16;
      bh[f] = *(const bf16x8*)(secBh + off);
      bl[f] = *(const bf16x8*)(secBl + off);
    }
#pragma unroll
    for (int fm = 0; fm < MF; ++fm)
#pragma unroll
      for (int fn = 0; fn < NF; ++fn) {
        acc[fm][fn] = __builtin_amdgcn_mfma_f32_16x16x32_bf16(ah[fm], bh[fn], acc[fm][fn], 0, 0, 0);
        acc[fm][fn] = __builtin_amdgcn_mfma_f32_16x16x32_bf16(ah[fm], bl[fn], acc[fm][fn], 0, 0, 0);
        acc[fm][fn] = __builtin_amdgcn_mfma_f32_16x16x32_bf16(al[fm], bh[fn], acc[fm][fn], 0, 0, 0);
      }
  };

  stage(0, 0);
  __syncthreads();
  int cur = 0;
  for (int kc = 0; kc < KTILES - 1; ++kc) {
    stage(cur ^ 1, kc + 1);   // issue next-tile loads first (overlap with compute)
    compute(cur);
    __syncthreads();          // drains vmcnt (stage) + lgkmcnt (ds_read)
    cur ^= 1;
  }
  compute(cur);

  // C/D layout (m89-verified): col = lane&15, row = (lane>>4)*4 + reg
#pragma unroll
  for (int fm = 0; fm < MF; ++fm)
#pragma unroll
    for (int fn = 0; fn < NF; ++fn)
#pragma unroll
      for (int r = 0; r < 4; ++r) {
        int ml = wm * (MF * 16) + fm * 16 + (lane >> 4) * 4 + r;
        int nl = wn * (NF * 16) + fn * 16 + lr;
        epi(ml, nl, acc[fm][fn][r]);
      }
}

// ---------------------------------------------------------------------------
// proj: z=0 Q=x@W1T, z=1 K=y@W2T, z=2 VW=y@W34T.  M=4096,N=512,K=512.
// 64x128 tiles, BK=32 x 16: grid (64, 4, 3) x 256 = 768 blocks, 48KB LDS (3/CU)
// ---------------------------------------------------------------------------
__global__ __launch_bounds__(256) void proj_gemm(
    const unsigned short* __restrict__ xh, const unsigned short* __restrict__ xl,
    const unsigned short* __restrict__ yh, const unsigned short* __restrict__ yl,
    const unsigned short* __restrict__ w1h, const unsigned short* __restrict__ w1l,
    const unsigned short* __restrict__ w2h, const unsigned short* __restrict__ w2l,
    const unsigned short* __restrict__ w34h, const unsigned short* __restrict__ w34l,
    unsigned short* qh, unsigned short* ql,
    unsigned short* kh, unsigned short* kl,
    unsigned short* vwh, unsigned short* vwl) {
  const int mt = blockIdx.x, nt = blockIdx.y, z = blockIdx.z;
  const unsigned short *Ahi, *Alo, *Bhi, *Blo;
  if (z == 0)      { Ahi = xh; Alo = xl; Bhi = w1h;  Blo = w1l; }
  else if (z == 1) { Ahi = yh; Alo = yl; Bhi = w2h;  Blo = w2l; }
  else             { Ahi = yh; Alo = yl; Bhi = w34h; Blo = w34l; }
  Ahi += (size_t)mt * 64 * 512;  Alo += (size_t)mt * 64 * 512;
  Bhi += (size_t)nt * 128 * 512; Blo += (size_t)nt * 128 * 512;

  gemm_core<64, 2, 4, 16>(Ahi, Alo, Bhi, Blo, 1024, [&](int ml, int nl, float v) {
    int row = mt * 64 + ml;           // (s, item)
    int col = nt * 128 + nl;          // (h, d|e)
    int s = row >> 7, n = row & 127;
    int h = col >> 6, d = col & 63;
    unsigned short hi, lo; split2(v, hi, lo);
    if (z == 0)      { int a = ((s * 8 + h) * 128 + n) * 64 + d; qh[a] = hi; ql[a] = lo; }
    else if (z == 1) { int a = ((s * 8 + h) * 128 + n) * 64 + d; kh[a] = hi; kl[a] = lo; }
    else             { int a = (s * 64 + d) * 1024 + h * 128 + n; vwh[a] = hi; vwl[a] = lo; }
  });
}

// ---------------------------------------------------------------------------
// attn: per (s,h): relu(Q K^T / 8)/128 -> A[(s*128+q)][(h*128+k)].  M=N=128,K=64.
// 64x128 tiles, BK=32 x 2: grid (64, 8) x 256 = 512 blocks
// ---------------------------------------------------------------------------
__global__ __launch_bounds__(256) void attn_gemm(
    const unsigned short* __restrict__ qh, const unsigned short* __restrict__ ql,
    const unsigned short* __restrict__ kh, const unsigned short* __restrict__ kl,
    unsigned short* ah, unsigned short* al) {
  const int s = blockIdx.x >> 1, msub = blockIdx.x & 1, h = blockIdx.y;
  const size_t offq = (size_t)(s * 8 + h) * 128 * 64 + (size_t)msub * 64 * 64;
  const size_t offk = (size_t)(s * 8 + h) * 128 * 64;
  gemm_core<64, 2, 4, 2>(qh + offq, ql + offq, kh + offk, kl + offk, 128,
                         [&](int ml, int nl, float v) {
    v = fmaxf(v * 0.125f, 0.f) * (1.0f / 128.0f);
    unsigned short hi, lo; split2(v, hi, lo);
    int q = msub * 64 + ml;
    int a = (s * 128 + q) * 1024 + h * 128 + nl;
    ah[a] = hi; al[a] = lo;
  });
}

// ---------------------------------------------------------------------------
// out: [4096,1024] @ [2048,1024]^T -> out[i,j,q,e].  M=4096,N=2048,K=1024.
// 128x128 tiles, BK=32 x 32: grid (32, 16) x 256 = 512 blocks, 64KB LDS (2/CU)
// ---------------------------------------------------------------------------
__global__ __launch_bounds__(256) void out_gemm(
    const unsigned short* __restrict__ ah, const unsigned short* __restrict__ al,
    const unsigned short* __restrict__ vwh, const unsigned short* __restrict__ vwl,
    float* __restrict__ out) {
  const int mt = blockIdx.x, nt = blockIdx.y;
  gemm_core<128, 4, 4, 32>(ah + (size_t)mt * 128 * 1024, al + (size_t)mt * 128 * 1024,
                           vwh + (size_t)nt * 128 * 1024, vwl + (size_t)nt * 128 * 1024, 2048,
                           [&](int ml, int nl, float v) {
                             int row = mt * 128 + ml;    // (j, q)
                             int col = nt * 128 + nl;    // (i, e)
                             int i = col >> 6, e = col & 63;
                             int j = row >> 7, q = row & 127;
                             out[(size_t)(((i * 32 + j) * 128 + q)) * 64 + e] = v;
                           });
}

// ---------------------------------------------------------------------------
extern "C" void kernel_launch(void* const* d_in, const int* in_sizes, int n_in,
                              void* d_out, int out_size, void* d_ws, size_t ws_size,
                              hipStream_t stream) {
  const float* x  = (const float*)d_in[0];
  const float* y  = (const float*)d_in[1];
  const float* W1 = (const float*)d_in[2];
  const float* W2 = (const float*)d_in[3];
  const float* W3 = (const float*)d_in[4];
  const float* W4 = (const float*)d_in[5];
  float* out = (float*)d_out;
  char* ws = (char*)d_ws;

  unsigned short* xh  = (unsigned short*)(ws + OFF_XH);
  unsigned short* xl  = (unsigned short*)(ws + OFF_XL);
  unsigned short* yh  = (unsigned short*)(ws + OFF_YH);
  unsigned short* yl  = (unsigned short*)(ws + OFF_YL);
  unsigned short* w1h = (unsigned short*)(ws + OFF_W1H);
  unsigned short* w1l = (unsigned short*)(ws + OFF_W1L);
  unsigned short* w2h = (unsigned short*)(ws + OFF_W2H);
  unsigned short* w2l = (unsigned short*)(ws + OFF_W2L);
  unsigned short* w3h = (unsigned short*)(ws + OFF_W3H);
  unsigned short* w3l = (unsigned short*)(ws + OFF_W3L);
  unsigned short* qh  = (unsigned short*)(ws + OFF_QH);
  unsigned short* ql  = (unsigned short*)(ws + OFF_QL);
  unsigned short* kh  = (unsigned short*)(ws + OFF_KH);
  unsigned short* kl  = (unsigned short*)(ws + OFF_KL);
  unsigned short* vwh = (unsigned short*)(ws + OFF_VWH);
  unsigned short* vwl = (unsigned short*)(ws + OFF_VWL);
  unsigned short* ah  = (unsigned short*)(ws + OFF_AH);   // aliases xh/xl region (dead after proj)
  unsigned short* al  = (unsigned short*)(ws + OFF_AL);   // aliases yh/yl region

  prep_all<<<4288, 256, 0, stream>>>(x, y, W1, W2, W3, W4,
                                     xh, xl, yh, yl, w1h, w1l, w2h, w2l, w3h, w3l);
  proj_gemm<<<dim3(64, 4, 3), 256, 0, stream>>>(xh, xl, yh, yl, w1h, w1l, w2h, w2l,
                                                w3h, w3l, qh, ql, kh, kl, vwh, vwl);
  attn_gemm<<<dim3(64, 8), 256, 0, stream>>>(qh, ql, kh, kl, ah, al);
  out_gemm<<<dim3(32, 16), 256, 0, stream>>>(ah, al, vwh, vwl, out);
}

// Round 7
// 169.775 us; speedup vs baseline: 1.4898x; 1.4898x over previous
//
#include <hip/hip_runtime.h>

// set_transform: out[i,j,q,e] = sum_{h,k} relu((x_j W1)[q,h,:]·(y_j W2)[k,h,:]/8)/128 * (y_i W34)[k,h,e]
// W34[c,h*64+e] = sum_d W3[c,h*64+d] W4[h*64+d,e]   (final @W4 fused into V-proj)
//
// R6/R7: numerics bf16-3-term-split -> PLAIN FP16 1-term (threshold 7.07e-3, 3-term
// measured 9.8e-4 = 7x over-engineered). MFMA work 72->24 GF, staging/LDS halved.
// Predicted absmax ~1e-3 (fp16 2^-11 mantissa; dominant path q/k rounding).
// Structure: 4 separate kernels (R5 cooperative fusion FAILED on cross-XCD
// visibility of stage N writes under grid.sync — kernel boundaries are the proven sync).
// GEMM core: R3-exact 2-barrier BK=64 linear-LDS (R4 proved T2-swizzle null here).

#define MB (1u << 20)

typedef __attribute__((ext_vector_type(8))) _Float16 half8;
typedef __attribute__((ext_vector_type(4))) _Float16 half4;
typedef __attribute__((ext_vector_type(4))) float f32x4;

enum : size_t {
  OFF_X   = 0,                        // x fp16 [4096][512], 4MB; reused as A[0:4MB) after proj
  OFF_Y   = OFF_X   + 4 * MB,         // y fp16, 4MB; reused as A[4MB:8MB)
  OFF_W1  = OFF_Y   + 4 * MB,         // W1T fp16 [512][512]
  OFF_W2  = OFF_W1  + 512 * 1024,
  OFF_W34 = OFF_W2  + 512 * 1024,     // W34T fp16 [512][512]
  OFF_Q   = OFF_W34 + 512 * 1024,     // [s][h][128][64], 4MB
  OFF_K   = OFF_Q   + 4 * MB,         // 4MB
  OFF_VW  = OFF_K   + 4 * MB,         // [(i*64+e)][h*128+n], 4MB
  WS_NEED = OFF_VW  + 4 * MB,         // 21.5MB
  OFF_A   = OFF_X                     // A fp16 [4096][1024], 8MB, aliases x|y (dead after proj)
};

#define GLOAD_LDS16(g, l)                                                    \
  __builtin_amdgcn_global_load_lds(                                          \
      (const __attribute__((address_space(1))) void*)(g),                    \
      (__attribute__((address_space(3))) void*)(l), 16, 0, 0)

// ---------------------------------------------------------------------------
// prep: b<4096: x,y f32 -> fp16 (float4/thread).
//       4096..4223: W1/W2 transpose via padded LDS; 4224..4287: W34 = per-head W3@W4.
// grid 4288 x 256
// ---------------------------------------------------------------------------
__global__ __launch_bounds__(256) void prep_all(
    const float* __restrict__ x, const float* __restrict__ y,
    const float* __restrict__ W1, const float* __restrict__ W2,
    const float* __restrict__ W3, const float* __restrict__ W4,
    _Float16* xc, _Float16* yc,
    _Float16* w1t, _Float16* w2t, _Float16* w34t) {
  int b = blockIdx.x;
  if (b < 4096) {
    int idx = b * 256 + threadIdx.x;
    const float4* src; _Float16* d; int t;
    if (idx < 524288) { src = (const float4*)x; d = xc; t = idx; }
    else              { src = (const float4*)y; d = yc; t = idx - 524288; }
    float4 v = src[t];
    half4 h = { (_Float16)v.x, (_Float16)v.y, (_Float16)v.z, (_Float16)v.w };
    *(half4*)&d[t * 4] = h;
    return;
  }
  b -= 4096;
  if (b < 128) {                       // W1/W2 transpose: out[n][c] = W[c][n]
    __shared__ float lt[64][65];
    const float* W = (b < 64) ? W1 : W2;
    _Float16* d   = (b < 64) ? w1t : w2t;
    int t = b & 63;
    int cb = (t >> 3) * 64, nb = (t & 7) * 64;
#pragma unroll
    for (int it = 0; it < 16; ++it) {
      int idx = it * 256 + threadIdx.x;
      int cl = idx >> 6, nl = idx & 63;
      lt[cl][nl] = W[(cb + cl) * 512 + nb + nl];   // coalesced in n
    }
    __syncthreads();
#pragma unroll
    for (int it = 0; it < 16; ++it) {
      int idx = it * 256 + threadIdx.x;
      int nl = idx >> 6, cl = idx & 63;
      d[(nb + nl) * 512 + cb + cl] = (_Float16)lt[cl][nl];   // coalesced in c
    }
  } else {                             // W34T[(h*64+e)][c] = sum_d W3[c][h*64+d]*W4[h*64+d][e]
    __shared__ float l3[64][65];       // [c_local][d]
    __shared__ float l4[64][65];       // [d][e]
    int t = b - 128;
    int h = t >> 3, cb = (t & 7) * 64;
#pragma unroll
    for (int it = 0; it < 16; ++it) {
      int idx = it * 256 + threadIdx.x;
      int r = idx >> 6, cidx = idx & 63;
      l3[r][cidx] = W3[(cb + r) * 512 + h * 64 + cidx];
      l4[r][cidx] = W4[(h * 64 + r) * 64 + cidx];
    }
    __syncthreads();
#pragma unroll
    for (int pass = 0; pass < 16; ++pass) {
      int cl = threadIdx.x & 63;
      int el = pass * 4 + (threadIdx.x >> 6);
      float acc = 0.f;
#pragma unroll
      for (int d = 0; d < 64; ++d)
        acc += l3[cl][d] * l4[d][el];
      w34t[(h * 64 + el) * 512 + cb + cl] = (_Float16)acc;
    }
  }
}

// ---------------------------------------------------------------------------
// GEMM core (R3-exact structure, fp16 1-term): BM x 128 tile, 4 waves (2x2),
// K in BK=64 chunks, single-buffer, stage -> barrier -> compute -> barrier.
// Linear LDS rows (64 fp16 = 128B). A,B row-major, k contiguous (NT form).
// ---------------------------------------------------------------------------
template <int BM, int MF, int NF, int KTILES, typename EPI>
__device__ __forceinline__ void gemm_core(
    const _Float16* __restrict__ A, const _Float16* __restrict__ B,
    int row_stride_bytes, EPI&& epi) {
  constexpr int BN = 2 * NF * 16;       // 128 (WN=2)
  constexpr int ABYTES = BM * 128;      // BM rows x 64 k x 2B
  constexpr int BBYTES = BN * 128;
  constexpr int TOTAL = ABYTES + BBYTES;
  constexpr int ITERS = TOTAL / 4096;   // 16B x 256 threads per iter
  static_assert(TOTAL % 4096 == 0 && ABYTES % 4096 == 0, "");
  __shared__ alignas(16) char smem[TOTAL];
  _Float16* sA = (_Float16*)smem;
  _Float16* sB = (_Float16*)(smem + ABYTES);

  const int tid  = threadIdx.x;
  const int lane = tid & 63;
  const int wid  = tid >> 6;
  const int wm   = wid >> 1, wn = wid & 1;
  const int lr   = lane & 15;
  const int lk   = (lane >> 4) * 8;

  f32x4 acc[MF][NF];
#pragma unroll
  for (int i = 0; i < MF; ++i)
#pragma unroll
    for (int j = 0; j < NF; ++j) acc[i][j] = (f32x4){0.f, 0.f, 0.f, 0.f};

  for (int kc = 0; kc < KTILES; ++kc) {
    if (kc) __syncthreads();
#pragma unroll
    for (int i = 0; i < ITERS; ++i) {
      int o = i * 4096 + wid * 1024 + lane * 16;   // flat byte offset
      const char* g; int lo_;
      if (o < ABYTES) { g = (const char*)A; lo_ = o; }
      else            { g = (const char*)B; lo_ = o - ABYTES; }
      GLOAD_LDS16(g + (size_t)(lo_ >> 7) * row_stride_bytes + kc * 128 + (lo_ & 127),
                  smem + i * 4096 + wid * 1024);
    }
    __syncthreads();
#pragma unroll
    for (int ks = 0; ks < 2; ++ks) {
      half8 a[MF], bfr[NF];
#pragma unroll
      for (int f = 0; f < MF; ++f)
        a[f] = *(const half8*)&sA[(wm * (MF * 16) + f * 16 + lr) * 64 + ks * 32 + lk];
#pragma unroll
      for (int f = 0; f < NF; ++f)
        bfr[f] = *(const half8*)&sB[(wn * (NF * 16) + f * 16 + lr) * 64 + ks * 32 + lk];
#pragma unroll
      for (int fm = 0; fm < MF; ++fm)
#pragma unroll
        for (int fn = 0; fn < NF; ++fn)
          acc[fm][fn] = __builtin_amdgcn_mfma_f32_16x16x32_f16(a[fm], bfr[fn], acc[fm][fn], 0, 0, 0);
    }
  }
  // C/D layout (m89-verified): col = lane&15, row = (lane>>4)*4 + reg
#pragma unroll
  for (int fm = 0; fm < MF; ++fm)
#pragma unroll
    for (int fn = 0; fn < NF; ++fn)
#pragma unroll
      for (int r = 0; r < 4; ++r) {
        int ml = wm * (MF * 16) + fm * 16 + (lane >> 4) * 4 + r;
        int nl = wn * (NF * 16) + fn * 16 + lr;
        epi(ml, nl, acc[fm][fn][r]);
      }
}

// ---------------------------------------------------------------------------
// proj: z=0 Q=x@W1T, z=1 K=y@W2T, z=2 VW=y@W34T.  M=4096,N=512,K=512.
// 64x128 tiles: grid (64, 4, 3) x 256 = 768 blocks (3/CU), LDS 24KB
// ---------------------------------------------------------------------------
__global__ __launch_bounds__(256) void proj_gemm(
    const _Float16* __restrict__ xc, const _Float16* __restrict__ yc,
    const _Float16* __restrict__ w1t, const _Float16* __restrict__ w2t,
    const _Float16* __restrict__ w34t,
    _Float16* q, _Float16* k, _Float16* vw) {
  const int mt = blockIdx.x, nt = blockIdx.y, z = blockIdx.z;
  const _Float16 *A, *B;
  if (z == 0)      { A = xc; B = w1t; }
  else if (z == 1) { A = yc; B = w2t; }
  else             { A = yc; B = w34t; }
  A += (size_t)mt * 64 * 512;
  B += (size_t)nt * 128 * 512;

  gemm_core<64, 2, 4, 8>(A, B, 1024, [&](int ml, int nl, float v) {
    int row = mt * 64 + ml;           // (s, item)
    int col = nt * 128 + nl;          // (h, d|e)
    int s = row >> 7, n = row & 127;
    int h = col >> 6, d = col & 63;
    _Float16 hv = (_Float16)v;
    if (z == 0)      q[((s * 8 + h) * 128 + n) * 64 + d] = hv;
    else if (z == 1) k[((s * 8 + h) * 128 + n) * 64 + d] = hv;
    else             vw[(s * 64 + d) * 1024 + h * 128 + n] = hv;
  });
}

// ---------------------------------------------------------------------------
// attn: per (s,h): relu(Q K^T / 8)/128 -> A[(s*128+q)][(h*128+k)].  M=N=128,K=64.
// 64x128 tiles: grid (64, 8) x 256 = 512 blocks, LDS 24KB
// ---------------------------------------------------------------------------
__global__ __launch_bounds__(256) void attn_gemm(
    const _Float16* __restrict__ q, const _Float16* __restrict__ k,
    _Float16* a) {
  const int s = blockIdx.x >> 1, msub = blockIdx.x & 1, h = blockIdx.y;
  const size_t offq = (size_t)(s * 8 + h) * 128 * 64 + (size_t)msub * 64 * 64;
  const size_t offk = (size_t)(s * 8 + h) * 128 * 64;
  gemm_core<64, 2, 4, 1>(q + offq, k + offk, 128, [&](int ml, int nl, float v) {
    v = fmaxf(v * 0.125f, 0.f) * (1.0f / 128.0f);
    int qq = msub * 64 + ml;
    a[(s * 128 + qq) * 1024 + h * 128 + nl] = (_Float16)v;
  });
}

// ---------------------------------------------------------------------------
// out: [4096,1024] @ [2048,1024]^T -> out[i,j,q,e].  M=4096,N=2048,K=1024.
// 128x128 tiles: grid (32, 16) x 256 = 512 blocks (2/CU), LDS 32KB
// ---------------------------------------------------------------------------
__global__ __launch_bounds__(256) void out_gemm(
    const _Float16* __restrict__ a, const _Float16* __restrict__ vw,
    float* __restrict__ out) {
  const int mt = blockIdx.x, nt = blockIdx.y;
  gemm_core<128, 4, 4, 16>(a + (size_t)mt * 128 * 1024,
                           vw + (size_t)nt * 128 * 1024, 2048,
                           [&](int ml, int nl, float v) {
                             int row = mt * 128 + ml;    // (j, q)
                             int col = nt * 128 + nl;    // (i, e)
                             int i = col >> 6, e = col & 63;
                             int j = row >> 7, qq = row & 127;
                             out[(size_t)(((i * 32 + j) * 128 + qq)) * 64 + e] = v;
                           });
}

// ---------------------------------------------------------------------------
extern "C" void kernel_launch(void* const* d_in, const int* in_sizes, int n_in,
                              void* d_out, int out_size, void* d_ws, size_t ws_size,
                              hipStream_t stream) {
  const float* x  = (const float*)d_in[0];
  const float* y  = (const float*)d_in[1];
  const float* W1 = (const float*)d_in[2];
  const float* W2 = (const float*)d_in[3];
  const float* W3 = (const float*)d_in[4];
  const float* W4 = (const float*)d_in[5];
  float* out = (float*)d_out;
  char* ws = (char*)d_ws;

  _Float16* xc   = (_Float16*)(ws + OFF_X);
  _Float16* yc   = (_Float16*)(ws + OFF_Y);
  _Float16* w1t  = (_Float16*)(ws + OFF_W1);
  _Float16* w2t  = (_Float16*)(ws + OFF_W2);
  _Float16* w34t = (_Float16*)(ws + OFF_W34);
  _Float16* q    = (_Float16*)(ws + OFF_Q);
  _Float16* k    = (_Float16*)(ws + OFF_K);
  _Float16* vw   = (_Float16*)(ws + OFF_VW);
  _Float16* a    = (_Float16*)(ws + OFF_A);   // aliases xc|yc (dead after proj)

  prep_all<<<4288, 256, 0, stream>>>(x, y, W1, W2, W3, W4, xc, yc, w1t, w2t, w34t);
  proj_gemm<<<dim3(64, 4, 3), 256, 0, stream>>>(xc, yc, w1t, w2t, w34t, q, k, vw);
  attn_gemm<<<dim3(64, 8), 256, 0, stream>>>(q, k, a);
  out_gemm<<<dim3(32, 16), 256, 0, stream>>>(a, vw, out);
}

// Round 8
// 145.681 us; speedup vs baseline: 1.7362x; 1.1654x over previous
//
#include <hip/hip_runtime.h>

// set_transform: out[i,j,q,e] = sum_{h,k} relu((x_j W1)[q,h,:]·(y_j W2)[k,h,:]/8)/128 * (y_i W34)[k,h,e]
// W34[c,h*64+e] = sum_d W3[c,h*64+d] W4[h*64+d,e]   (final @W4 fused into V-proj)
//
// R8: R7 profile showed fused prep_all = 50us @ 4.7% occupancy (VGPR 208 from the
// unrolled W34 branch + 50KB LDS union taxed all 4288 blocks). Split back into
// prep_xy (no LDS, ~16 VGPR, 16B stores) + prep_w (192 blocks, pass-loop not unrolled).
// Numerics: plain fp16 1-term MFMA (R7 validated: absmax 1.95e-3 < 7.07e-3 threshold).
// GEMM core: R3-exact 2-barrier BK=64 linear-LDS (R4: T2-swizzle null at 2-phase;
// R5: cooperative fusion breaks cross-XCD visibility — kernel boundaries stay).

#define MB (1u << 20)

typedef __attribute__((ext_vector_type(8))) _Float16 half8;
typedef __attribute__((ext_vector_type(4))) _Float16 half4;
typedef __attribute__((ext_vector_type(4))) float f32x4;

enum : size_t {
  OFF_X   = 0,                        // x fp16 [4096][512], 4MB; reused as A[0:4MB) after proj
  OFF_Y   = OFF_X   + 4 * MB,         // y fp16, 4MB; reused as A[4MB:8MB)
  OFF_W1  = OFF_Y   + 4 * MB,         // W1T fp16 [512][512]
  OFF_W2  = OFF_W1  + 512 * 1024,
  OFF_W34 = OFF_W2  + 512 * 1024,     // W34T fp16 [512][512]
  OFF_Q   = OFF_W34 + 512 * 1024,     // [s][h][128][64], 4MB
  OFF_K   = OFF_Q   + 4 * MB,         // 4MB
  OFF_VW  = OFF_K   + 4 * MB,         // [(i*64+e)][h*128+n], 4MB
  WS_NEED = OFF_VW  + 4 * MB,         // 21.5MB
  OFF_A   = OFF_X                     // A fp16 [4096][1024], 8MB, aliases x|y (dead after proj)
};

#define GLOAD_LDS16(g, l)                                                    \
  __builtin_amdgcn_global_load_lds(                                          \
      (const __attribute__((address_space(1))) void*)(g),                    \
      (__attribute__((address_space(3))) void*)(l), 16, 0, 0)

// ---------------------------------------------------------------------------
// prep_xy: x,y f32 -> fp16. 8 floats/thread: 2x float4 load, 1x half8 (16B) store.
// grid 2048 x 256, no LDS, minimal VGPR -> full occupancy, HBM-bound (~5us).
// ---------------------------------------------------------------------------
__global__ __launch_bounds__(256) void prep_xy(
    const float* __restrict__ x, const float* __restrict__ y,
    _Float16* xc, _Float16* yc) {
  int idx = blockIdx.x * 256 + threadIdx.x;      // 0..524287
  const float4* src; _Float16* d; int t;
  if (idx < 262144) { src = (const float4*)x; d = xc; t = idx; }
  else              { src = (const float4*)y; d = yc; t = idx - 262144; }
  float4 v0 = src[2 * t], v1 = src[2 * t + 1];
  half8 h = { (_Float16)v0.x, (_Float16)v0.y, (_Float16)v0.z, (_Float16)v0.w,
              (_Float16)v1.x, (_Float16)v1.y, (_Float16)v1.z, (_Float16)v1.w };
  *(half8*)&d[t * 8] = h;
}

// ---------------------------------------------------------------------------
// prep_w: b<128: W1/W2 transpose via padded LDS; b>=128: W34 = per-head W3@W4.
// grid 192 x 256. Pass loops NOT unrolled (R7: full unroll drove VGPR to 208).
// ---------------------------------------------------------------------------
__global__ __launch_bounds__(256) void prep_w(
    const float* __restrict__ W1, const float* __restrict__ W2,
    const float* __restrict__ W3, const float* __restrict__ W4,
    _Float16* w1t, _Float16* w2t, _Float16* w34t) {
  int b = blockIdx.x;
  if (b < 128) {                       // W1/W2 transpose: out[n][c] = W[c][n]
    __shared__ float lt[64][65];
    const float* W = (b < 64) ? W1 : W2;
    _Float16* d   = (b < 64) ? w1t : w2t;
    int t = b & 63;
    int cb = (t >> 3) * 64, nb = (t & 7) * 64;
    for (int it = 0; it < 16; ++it) {
      int idx = it * 256 + threadIdx.x;
      int cl = idx >> 6, nl = idx & 63;
      lt[cl][nl] = W[(cb + cl) * 512 + nb + nl];   // coalesced in n
    }
    __syncthreads();
    for (int it = 0; it < 16; ++it) {
      int idx = it * 256 + threadIdx.x;
      int nl = idx >> 6, cl = idx & 63;
      d[(nb + nl) * 512 + cb + cl] = (_Float16)lt[cl][nl];   // coalesced in c
    }
  } else {                             // W34T[(h*64+e)][c] = sum_d W3[c][h*64+d]*W4[h*64+d][e]
    __shared__ float l3[64][65];       // [c_local][d]
    __shared__ float l4[64][65];       // [d][e]
    int t = b - 128;
    int h = t >> 3, cb = (t & 7) * 64;
    for (int it = 0; it < 16; ++it) {
      int idx = it * 256 + threadIdx.x;
      int r = idx >> 6, cidx = idx & 63;
      l3[r][cidx] = W3[(cb + r) * 512 + h * 64 + cidx];
      l4[r][cidx] = W4[(h * 64 + r) * 64 + cidx];
    }
    __syncthreads();
    for (int pass = 0; pass < 16; ++pass) {       // not unrolled: keep VGPR low
      int cl = threadIdx.x & 63;
      int el = pass * 4 + (threadIdx.x >> 6);
      float acc = 0.f;
#pragma unroll
      for (int d = 0; d < 64; ++d)
        acc += l3[cl][d] * l4[d][el];
      w34t[(h * 64 + el) * 512 + cb + cl] = (_Float16)acc;
    }
  }
}

// ---------------------------------------------------------------------------
// GEMM core (R3-exact structure, fp16 1-term): BM x 128 tile, 4 waves (2x2),
// K in BK=64 chunks, single-buffer, stage -> barrier -> compute -> barrier.
// Linear LDS rows (64 fp16 = 128B). A,B row-major, k contiguous (NT form).
// ---------------------------------------------------------------------------
template <int BM, int MF, int NF, int KTILES, typename EPI>
__device__ __forceinline__ void gemm_core(
    const _Float16* __restrict__ A, const _Float16* __restrict__ B,
    int row_stride_bytes, EPI&& epi) {
  constexpr int BN = 2 * NF * 16;       // 128 (WN=2)
  constexpr int ABYTES = BM * 128;      // BM rows x 64 k x 2B
  constexpr int BBYTES = BN * 128;
  constexpr int TOTAL = ABYTES + BBYTES;
  constexpr int ITERS = TOTAL / 4096;   // 16B x 256 threads per iter
  static_assert(TOTAL % 4096 == 0 && ABYTES % 4096 == 0, "");
  __shared__ alignas(16) char smem[TOTAL];
  _Float16* sA = (_Float16*)smem;
  _Float16* sB = (_Float16*)(smem + ABYTES);

  const int tid  = threadIdx.x;
  const int lane = tid & 63;
  const int wid  = tid >> 6;
  const int wm   = wid >> 1, wn = wid & 1;
  const int lr   = lane & 15;
  const int lk   = (lane >> 4) * 8;

  f32x4 acc[MF][NF];
#pragma unroll
  for (int i = 0; i < MF; ++i)
#pragma unroll
    for (int j = 0; j < NF; ++j) acc[i][j] = (f32x4){0.f, 0.f, 0.f, 0.f};

  for (int kc = 0; kc < KTILES; ++kc) {
    if (kc) __syncthreads();
#pragma unroll
    for (int i = 0; i < ITERS; ++i) {
      int o = i * 4096 + wid * 1024 + lane * 16;   // flat byte offset
      const char* g; int lo_;
      if (o < ABYTES) { g = (const char*)A; lo_ = o; }
      else            { g = (const char*)B; lo_ = o - ABYTES; }
      GLOAD_LDS16(g + (size_t)(lo_ >> 7) * row_stride_bytes + kc * 128 + (lo_ & 127),
                  smem + i * 4096 + wid * 1024);
    }
    __syncthreads();
#pragma unroll
    for (int ks = 0; ks < 2; ++ks) {
      half8 a[MF], bfr[NF];
#pragma unroll
      for (int f = 0; f < MF; ++f)
        a[f] = *(const half8*)&sA[(wm * (MF * 16) + f * 16 + lr) * 64 + ks * 32 + lk];
#pragma unroll
      for (int f = 0; f < NF; ++f)
        bfr[f] = *(const half8*)&sB[(wn * (NF * 16) + f * 16 + lr) * 64 + ks * 32 + lk];
#pragma unroll
      for (int fm = 0; fm < MF; ++fm)
#pragma unroll
        for (int fn = 0; fn < NF; ++fn)
          acc[fm][fn] = __builtin_amdgcn_mfma_f32_16x16x32_f16(a[fm], bfr[fn], acc[fm][fn], 0, 0, 0);
    }
  }
  // C/D layout (m89-verified): col = lane&15, row = (lane>>4)*4 + reg
#pragma unroll
  for (int fm = 0; fm < MF; ++fm)
#pragma unroll
    for (int fn = 0; fn < NF; ++fn)
#pragma unroll
      for (int r = 0; r < 4; ++r) {
        int ml = wm * (MF * 16) + fm * 16 + (lane >> 4) * 4 + r;
        int nl = wn * (NF * 16) + fn * 16 + lr;
        epi(ml, nl, acc[fm][fn][r]);
      }
}

// ---------------------------------------------------------------------------
// proj: z=0 Q=x@W1T, z=1 K=y@W2T, z=2 VW=y@W34T.  M=4096,N=512,K=512.
// 64x128 tiles: grid (64, 4, 3) x 256 = 768 blocks (3/CU), LDS 24KB
// ---------------------------------------------------------------------------
__global__ __launch_bounds__(256) void proj_gemm(
    const _Float16* __restrict__ xc, const _Float16* __restrict__ yc,
    const _Float16* __restrict__ w1t, const _Float16* __restrict__ w2t,
    const _Float16* __restrict__ w34t,
    _Float16* q, _Float16* k, _Float16* vw) {
  const int mt = blockIdx.x, nt = blockIdx.y, z = blockIdx.z;
  const _Float16 *A, *B;
  if (z == 0)      { A = xc; B = w1t; }
  else if (z == 1) { A = yc; B = w2t; }
  else             { A = yc; B = w34t; }
  A += (size_t)mt * 64 * 512;
  B += (size_t)nt * 128 * 512;

  gemm_core<64, 2, 4, 8>(A, B, 1024, [&](int ml, int nl, float v) {
    int row = mt * 64 + ml;           // (s, item)
    int col = nt * 128 + nl;          // (h, d|e)
    int s = row >> 7, n = row & 127;
    int h = col >> 6, d = col & 63;
    _Float16 hv = (_Float16)v;
    if (z == 0)      q[((s * 8 + h) * 128 + n) * 64 + d] = hv;
    else if (z == 1) k[((s * 8 + h) * 128 + n) * 64 + d] = hv;
    else             vw[(s * 64 + d) * 1024 + h * 128 + n] = hv;
  });
}

// ---------------------------------------------------------------------------
// attn: per (s,h): relu(Q K^T / 8)/128 -> A[(s*128+q)][(h*128+k)].  M=N=128,K=64.
// 64x128 tiles: grid (64, 8) x 256 = 512 blocks, LDS 24KB
// ---------------------------------------------------------------------------
__global__ __launch_bounds__(256) void attn_gemm(
    const _Float16* __restrict__ q, const _Float16* __restrict__ k,
    _Float16* a) {
  const int s = blockIdx.x >> 1, msub = blockIdx.x & 1, h = blockIdx.y;
  const size_t offq = (size_t)(s * 8 + h) * 128 * 64 + (size_t)msub * 64 * 64;
  const size_t offk = (size_t)(s * 8 + h) * 128 * 64;
  gemm_core<64, 2, 4, 1>(q + offq, k + offk, 128, [&](int ml, int nl, float v) {
    v = fmaxf(v * 0.125f, 0.f) * (1.0f / 128.0f);
    int qq = msub * 64 + ml;
    a[(s * 128 + qq) * 1024 + h * 128 + nl] = (_Float16)v;
  });
}

// ---------------------------------------------------------------------------
// out: [4096,1024] @ [2048,1024]^T -> out[i,j,q,e].  M=4096,N=2048,K=1024.
// 128x128 tiles: grid (32, 16) x 256 = 512 blocks (2/CU), LDS 32KB
// ---------------------------------------------------------------------------
__global__ __launch_bounds__(256) void out_gemm(
    const _Float16* __restrict__ a, const _Float16* __restrict__ vw,
    float* __restrict__ out) {
  const int mt = blockIdx.x, nt = blockIdx.y;
  gemm_core<128, 4, 4, 16>(a + (size_t)mt * 128 * 1024,
                           vw + (size_t)nt * 128 * 1024, 2048,
                           [&](int ml, int nl, float v) {
                             int row = mt * 128 + ml;    // (j, q)
                             int col = nt * 128 + nl;    // (i, e)
                             int i = col >> 6, e = col & 63;
                             int j = row >> 7, qq = row & 127;
                             out[(size_t)(((i * 32 + j) * 128 + qq)) * 64 + e] = v;
                           });
}

// ---------------------------------------------------------------------------
extern "C" void kernel_launch(void* const* d_in, const int* in_sizes, int n_in,
                              void* d_out, int out_size, void* d_ws, size_t ws_size,
                              hipStream_t stream) {
  const float* x  = (const float*)d_in[0];
  const float* y  = (const float*)d_in[1];
  const float* W1 = (const float*)d_in[2];
  const float* W2 = (const float*)d_in[3];
  const float* W3 = (const float*)d_in[4];
  const float* W4 = (const float*)d_in[5];
  float* out = (float*)d_out;
  char* ws = (char*)d_ws;

  _Float16* xc   = (_Float16*)(ws + OFF_X);
  _Float16* yc   = (_Float16*)(ws + OFF_Y);
  _Float16* w1t  = (_Float16*)(ws + OFF_W1);
  _Float16* w2t  = (_Float16*)(ws + OFF_W2);
  _Float16* w34t = (_Float16*)(ws + OFF_W34);
  _Float16* q    = (_Float16*)(ws + OFF_Q);
  _Float16* k    = (_Float16*)(ws + OFF_K);
  _Float16* vw   = (_Float16*)(ws + OFF_VW);
  _Float16* a    = (_Float16*)(ws + OFF_A);   // aliases xc|yc (dead after proj)

  prep_w<<<192, 256, 0, stream>>>(W1, W2, W3, W4, w1t, w2t, w34t);
  prep_xy<<<2048, 256, 0, stream>>>(x, y, xc, yc);
  proj_gemm<<<dim3(64, 4, 3), 256, 0, stream>>>(xc, yc, w1t, w2t, w34t, q, k, vw);
  attn_gemm<<<dim3(64, 8), 256, 0, stream>>>(q, k, a);
  out_gemm<<<dim3(32, 16), 256, 0, stream>>>(a, vw, out);
}